// Round 9
// baseline (195.705 us; speedup 1.0000x reference)
//
#include <hip/hip_runtime.h>
#include <hip/hip_fp16.h>
#include <cstdint>
#include <cstddef>

#define T_DIM 5
#define F_DIM 8
#define Z_DIM 16
#define Y_DIM 96
#define X_DIM 96
#define NRAYS 32768
#define K_SAMP 128

// Pipeline (4 launches):
//   setup     : fused {transpose -> inp f16 [t][y][x][ci]} + {prep -> wB,bR} + {nearfar}
//   conv_mfma : fld f32 [t][zo][y][x] via v_mfma_f32_16x16x32_f16
//               LDS-free, 9-deep batched L2 loads per (p,kt) group (r8 was serial
//               load->use: MfmaUtil 2.6%, 95% stall; this is the ILP fix)
//   pack      : fld -> cellp, cells stored as (lo, hi-lo) half2 pairs
//   render    : 8 lanes/ray x 16 samples, grid-space march, log2 optics,
//               exec-masked cached cell reload

struct __align__(16) Cell { __half2 h0, h1, h2, h3; };

typedef __attribute__((ext_vector_type(4))) float     f32x4;
typedef __attribute__((ext_vector_type(8))) _Float16  f16x8;

__device__ __forceinline__ float fexp2(float x) { return __builtin_amdgcn_exp2f(x); }   // v_exp_f32
__device__ __forceinline__ float flog2(float x) { return __builtin_amdgcn_logf(x); }    // v_log_f32

// blocks [0,480): transpose | [480,696): weight prep | [696,1336): nearfar
__global__ __launch_bounds__(256) void setup_kernel(
        const float* __restrict__ xin, __half* __restrict__ inp,
        const float* __restrict__ w, const float* __restrict__ cb,
        const float* __restrict__ dw, __half* __restrict__ wB, float* __restrict__ bR,
        const float* __restrict__ ro, const float* __restrict__ rd,
        float* __restrict__ nearA, float* __restrict__ farA) {
    int b = blockIdx.x;
    if (b < 480) {
        // ---- transpose: inp[((t*96+y)*96+x)*128 + f*16+z] = (half) vol[f][t][z][y][x]
        __shared__ __half lds[96 * 136];
        int t = b / 96, y = b - (b / 96) * 96;
        for (int i = threadIdx.x; i < 12288; i += 256) {
            int row = i / 96;
            int x   = i - row * 96;
            int f = row >> 4, z = row & 15;
            float v = xin[(((size_t)(f * 5 + t) * 16 + z) * 96 + y) * 96 + x];
            lds[x * 136 + row] = __float2half(v);
        }
        __syncthreads();
        __half* ob = inp + ((size_t)(t * 96 + y) * 96) * 128;
        for (int c = threadIdx.x; c < 1536; c += 256) {
            int x = c >> 4, sub = c & 15;
            uint4 v = *(const uint4*)(lds + x * 136 + sub * 8);
            *(uint4*)(ob + (size_t)x * 128 + sub * 8) = v;
        }
    } else if (b < 696) {
        // ---- weight prep: wB[((p*27+tap)*16+zo)*32+cs], ci = p*32+cs
        int i = (b - 480) * 256 + threadIdx.x;       // 0 .. 55295 exactly
        if (i < 16) {
            float s = 0.f;
            #pragma unroll
            for (int f = 0; f < 8; ++f) s += cb[f * 16 + i] * dw[f];
            bR[i] = s;
        }
        int cs  = i & 31;
        int zo  = (i >> 5) & 15;
        int pt  = i >> 9;
        int p   = pt / 27;
        int tap = pt - p * 27;
        int ci  = p * 32 + cs;
        float s = 0.f;
        #pragma unroll
        for (int f = 0; f < 8; ++f)
            s += w[(size_t)((f * 16 + zo) * 128 + ci) * 27 + tap] * dw[f];
        wB[i] = __float2half(s);
    } else {
        // ---- nearfar: per-ray near/far only
        int gid = (b - 696) * 256 + threadIdx.x;     // 0 .. 163839
        const float* o = ro + (size_t)gid * 3;
        const float* d = rd + (size_t)gid * 3;
        float ox = o[0], oy = o[1], oz = o[2];
        float dx = d[0], dy = d[1], dz = d[2];
        float t1x = (0.f - ox) / dx, t2x = (1.f - ox) / dx;
        float t1y = (0.f - oy) / dy, t2y = (1.f - oy) / dy;
        float t1z = (0.f - oz) / dz, t2z = (1.f - oz) / dz;
        float nr = fmaxf(fmaxf(fminf(t1x, t2x), fminf(t1y, t2y)), fminf(t1z, t2z));
        float fr = fminf(fminf(fmaxf(t1x, t2x), fmaxf(t1y, t2y)), fmaxf(t1z, t2z));
        nr = fmaxf(nr, 0.01f);
        fr = fmaxf(fr, nr + 1e-6f);
        nearA[gid] = nr;
        farA[gid]  = fr;
    }
}

// Block = (t, y, 32-x seg), 128 thr = 2 waves; wave xt handles one 16-x MFMA tile.
// NO LDS, NO barriers. Per (p,kt) group: ALL 9 B fragments (3ky x 3kx) + 9 weight
// fragments are loaded into registers BEFORE any MFMA -> 18 loads in flight, one
// latency per group instead of per MFMA (r8's serial load->use was the 95% stall).
// Boundaries branch-free to keep the batch: y rows clamped + uniform-zeroed,
// x edges cndmask-zeroed (zero fragment contributes zero). kt skip is wave-uniform.
__global__ __launch_bounds__(128, 3) void conv_mfma_kernel(
        const __half* __restrict__ inp, const __half* __restrict__ wB,
        const float* __restrict__ bR, float* __restrict__ fld) {
    int bid = blockIdx.x;
    int wg  = (bid & 7) * 180 + (bid >> 3);      // bijective XCD swizzle (1440 = 8*180)
    int xs  = wg % 3;
    int rem = wg / 3;
    int y   = rem % 96;
    int t   = rem / 96;

    const int xt   = threadIdx.x >> 6;           // wave id: x-tile 0/1
    const int lane = threadIdx.x & 63;
    const int l15  = lane & 15;
    const int ksub = lane >> 4;
    const int xb   = xs * 32 + xt * 16;          // tile x base

    // per-lane x handling (loop-invariant)
    const bool ok0 = (xb + l15 - 1) >= 0;        // false only xb==0 && l15==0
    const bool ok2 = (xb + l15 + 1) < 96;        // false only xb==80 && l15==15
    const int xh0 = max(xb + l15 - 1, 0) << 7;   // half offsets (x*128)
    const int xh1 = (xb + l15) << 7;
    const int xh2 = min(xb + l15 + 1, 95) << 7;

    // clamped row indices (y-OOB rows zeroed uniformly after load)
    const int ym = max(y - 1, 0), yp = min(y + 1, 95);

    f32x4 accA = {0.f, 0.f, 0.f, 0.f};
    f32x4 accB = {0.f, 0.f, 0.f, 0.f};
    const int ko = ksub * 8;                     // k-slice half offset (16B)
    const uint4 Z = make_uint4(0u, 0u, 0u, 0u);

    #pragma unroll
    for (int p = 0; p < 4; ++p) {
        const __half* wpb = wB + p * 13824 + l15 * 32 + ko;
        #pragma unroll
        for (int kt = 0; kt < 3; ++kt) {
            int tt = t + kt - 1;
            if ((unsigned)tt >= 5u) continue;                    // wave-uniform skip
            const __half* tb = inp + (size_t)tt * 1179648 + (p << 5) + ko;
            const __half* r0 = tb + (size_t)ym * 12288;
            const __half* r1 = tb + (size_t)y  * 12288;
            const __half* r2 = tb + (size_t)yp * 12288;

            // ---- batch: 9 B-fragment loads (L2), then 9 weight loads (L1) ----
            uint4 bb[9];
            bb[0] = *(const uint4*)(r0 + xh0);
            bb[1] = *(const uint4*)(r0 + xh1);
            bb[2] = *(const uint4*)(r0 + xh2);
            bb[3] = *(const uint4*)(r1 + xh0);
            bb[4] = *(const uint4*)(r1 + xh1);
            bb[5] = *(const uint4*)(r1 + xh2);
            bb[6] = *(const uint4*)(r2 + xh0);
            bb[7] = *(const uint4*)(r2 + xh1);
            bb[8] = *(const uint4*)(r2 + xh2);
            f16x8 aw[9];
            #pragma unroll
            for (int j = 0; j < 9; ++j)
                aw[j] = *(const f16x8*)(wpb + (kt * 9 + j) * 512);

            // ---- boundary zero fixups (block-uniform y; per-lane x edges) ----
            if (y == 0)  { bb[0] = Z; bb[1] = Z; bb[2] = Z; }
            if (y == 95) { bb[6] = Z; bb[7] = Z; bb[8] = Z; }
            if (!ok0) { bb[0] = Z; bb[3] = Z; bb[6] = Z; }
            if (!ok2) { bb[2] = Z; bb[5] = Z; bb[8] = Z; }

            // ---- 9 MFMAs, alternating accumulator chains ----
            #pragma unroll
            for (int j = 0; j < 9; ++j) {
                f16x8 bfrag = *(f16x8*)&bb[j];
                if (j & 1) accB = __builtin_amdgcn_mfma_f32_16x16x32_f16(aw[j], bfrag, accB, 0, 0, 0);
                else       accA = __builtin_amdgcn_mfma_f32_16x16x32_f16(aw[j], bfrag, accA, 0, 0, 0);
            }
        }
    }

    // ---- epilogue: D[row=zo=(ksub*4+r)][col=x=l15]; 64B lane-contiguous stores ----
    #pragma unroll
    for (int r = 0; r < 4; ++r) {
        int zo = ksub * 4 + r;
        float bz = bR[zo];
        size_t o = (((size_t)t * 16 + zo) * 96 + y) * 96 + xb + l15;
        fld[o] = accA[r] + accB[r] + bz;
    }
}

// cellp[t][z][y][x]: 4 half2 of (lo, hi-lo) along x for the 4 (z,y) corner rows.
__global__ __launch_bounds__(256) void pack_kernel(
        const float* __restrict__ fld, Cell* __restrict__ cellp) {
    int i = blockIdx.x * 256 + threadIdx.x;
    if (i >= 737280) return;
    int x = i % 96;
    int r = i / 96;
    int y = r % 96;
    int r2 = r / 96;
    int z = r2 % 16;
    int t = r2 / 16;
    const float* ft = fld + (size_t)t * 147456;
    int xp = min(x + 1, 95);
    int yr0 = y * 96, yr1 = min(y + 1, 95) * 96;
    int zr0 = z * 9216, zr1 = min(z + 1, 15) * 9216;
    float c000 = ft[zr0 + yr0 + x], c001 = ft[zr0 + yr0 + xp];
    float c010 = ft[zr0 + yr1 + x], c011 = ft[zr0 + yr1 + xp];
    float c100 = ft[zr1 + yr0 + x], c101 = ft[zr1 + yr0 + xp];
    float c110 = ft[zr1 + yr1 + x], c111 = ft[zr1 + yr1 + xp];
    Cell cl;
    cl.h0 = __floats2half2_rn(c000, c001 - c000);
    cl.h1 = __floats2half2_rn(c010, c011 - c010);
    cl.h2 = __floats2half2_rn(c100, c101 - c100);
    cl.h3 = __floats2half2_rn(c110, c111 - c110);
    cellp[i] = cl;
}

// 8 lanes per ray, 16 samples each. Grid-space march; log2-domain optics;
// exec-masked cached cell reload (proven-minimal gather shape).
__global__ __launch_bounds__(256) void render_kernel(
        const float* __restrict__ ro, const float* __restrict__ rd,
        const Cell* __restrict__ cellp,
        const float* __restrict__ nearA, const float* __restrict__ farA,
        const float* __restrict__ dens_b, float* __restrict__ out) {
    int b = blockIdx.x;                 // 0..5119
    int b7 = b & 7, bhi = b >> 3;       // bhi 0..639
    int t, seg;
    if (b7 < 5) { t = b7; seg = bhi; }                       // XCD 0..4: one t each
    else { int j = (b7 - 5) * 640 + bhi; t = j / 384; seg = 640 + j % 384; }
    int c = threadIdx.x & 7;
    int ray = t * NRAYS + seg * 32 + (threadIdx.x >> 3);

    const float* o = ro + (size_t)ray * 3;
    const float* d = rd + (size_t)ray * 3;
    float ox = o[0], oy = o[1], oz = o[2];
    float dx = d[0], dy = d[1], dz = d[2];
    float nr = nearA[ray], fr = farA[ray];
    const Cell* vt = cellp + (size_t)t * 147456;
    const float L2E = 1.4426950408889634f;
    float db2 = dens_b[0] * L2E;

    float span = fr - nr;
    float step = span * 0.0078125f;
    float s  = fmaf((float)(c * 16), step, nr);
    float mid = s + 0.5f * step;
    float pxg = fmaf(dx, mid, ox) * 95.f;
    float pyg = fmaf(dy, mid, oy) * 95.f;
    float pzg = fmaf(dz, mid, oz) * 15.f;
    float ddxg = dx * step * 95.f, ddyg = dy * step * 95.f, ddzg = dz * step * 15.f;

    float num = 0.f, den = 0.f, A2 = 0.f;
    float trans = 1.f;
    int pidx = -1;
    Cell cl;
    for (int kk = 0; kk < 16; ++kk) {
        // consumed samples are in-box -> int clamps suffice (fracs identical)
        int x0 = min(max((int)pxg, 0), 94);
        int y0 = min(max((int)pyg, 0), 94);
        int z0 = min(max((int)pzg, 0), 14);
        float fx = pxg - (float)x0, fy = pyg - (float)y0, fz = pzg - (float)z0;

        int idx = z0 * 9216 + y0 * 96 + x0;
        if (idx != pidx) {                 // exec-masked 16B gather, changed lanes only
            pidx = idx;
            cl = vt[idx];
        }

        // (lo, hi-lo) packed cells -> v_fma_mix lerps
        float v00 = fmaf(fx, __half2float(__high2half(cl.h0)), __half2float(__low2half(cl.h0)));
        float v01 = fmaf(fx, __half2float(__high2half(cl.h1)), __half2float(__low2half(cl.h1)));
        float v10 = fmaf(fx, __half2float(__high2half(cl.h2)), __half2float(__low2half(cl.h2)));
        float v11 = fmaf(fx, __half2float(__high2half(cl.h3)), __half2float(__low2half(cl.h3)));
        float v0  = fmaf(fy, v01 - v00, v00);
        float v1  = fmaf(fy, v11 - v10, v10);
        float pre2 = fmaf(fmaf(fz, v1 - v0, v0), L2E, db2);      // (pre+db)*log2e

        float u = fexp2(-fabsf(pre2));
        float dens2 = fmaxf(pre2, 0.f) + flog2(1.f + u);         // softplus * log2e
        float dd2 = dens2 * step;                                 // dd * log2e
        float ex = fexp2(-dd2);                                   // exp(-dd)
        float wgt = (1.f - ex) * trans;
        num = fmaf(wgt, s, num);
        den += wgt;
        trans *= ex;
        A2 += dd2;
        s += step; pxg += ddxg; pyg += ddyg; pzg += ddzg;
    }
    // prefix transmittance across the 8 chunks of this ray
    int lane = threadIdx.x & 63;
    int qb = lane & ~7;
    float P = 0.f;
    #pragma unroll
    for (int j = 0; j < 7; ++j) {
        float Aj = __shfl(A2, qb + j, 64);
        P += (c > j) ? Aj : 0.f;
    }
    float sc = fexp2(-P);
    float numc = num * sc;
    float denc = den * sc;
    numc += __shfl_xor(numc, 1, 64);
    numc += __shfl_xor(numc, 2, 64);
    numc += __shfl_xor(numc, 4, 64);
    denc += __shfl_xor(denc, 1, 64);
    denc += __shfl_xor(denc, 2, 64);
    denc += __shfl_xor(denc, 4, 64);
    if (c == 0) {
        float depth = numc / (denc + 1e-10f);
        // per-ray clamp [near, s_last]; equals ref's global clamp to ~1e-8
        float slast = fmaf(0.9921875f, span, nr);
        depth = fminf(fmaxf(depth, nr), slast);
        out[ray] = depth;
    }
}

extern "C" void kernel_launch(void* const* d_in, const int* in_sizes, int n_in,
                              void* d_out, int out_size, void* d_ws, size_t ws_size,
                              hipStream_t stream) {
    const float* vol = (const float*)d_in[0];
    const float* ro  = (const float*)d_in[1];
    const float* rd  = (const float*)d_in[2];
    const float* cw  = (const float*)d_in[3];
    const float* cb  = (const float*)d_in[4];
    const float* dw  = (const float*)d_in[5];
    const float* dbp = (const float*)d_in[6];
    float* out = (float*)d_out;

    float* ws      = (float*)d_ws;
    float* fld     = ws;                                    // [0 .. 737,280)
    __half* inp    = (__half*)(ws + 737280);                // 5,898,240 halves
    Cell*  cellp   = (Cell*)(ws + 737280);                  // overlaps dead inp
    __half* wB     = (__half*)(ws + 737280 + 2949120);      // 55,296 halves
    float* bR      = ws + 737280 + 2949120 + 27648;         // 16 (+pad to 32)
    float* nearA   = bR + 32;
    float* farA    = nearA + 163840;

    hipLaunchKernelGGL(setup_kernel, dim3(1336), dim3(256), 0, stream,
                       vol, inp, cw, cb, dw, wB, bR, ro, rd, nearA, farA);
    hipLaunchKernelGGL(conv_mfma_kernel, dim3(1440), dim3(128), 0, stream,
                       inp, wB, bR, fld);
    hipLaunchKernelGGL(pack_kernel, dim3(2880), dim3(256), 0, stream, fld, cellp);
    hipLaunchKernelGGL(render_kernel, dim3(5120), dim3(256), 0, stream,
                       ro, rd, cellp, nearA, farA, dbp, out);
}

// Round 10
// 160.989 us; speedup vs baseline: 1.2156x; 1.2156x over previous
//
#include <hip/hip_runtime.h>
#include <hip/hip_fp16.h>
#include <cstdint>
#include <cstddef>

#define T_DIM 5
#define F_DIM 8
#define Z_DIM 16
#define Y_DIM 96
#define X_DIM 96
#define NRAYS 32768
#define K_SAMP 128

// Pipeline (5 launches):
//   setup     : fused {transpose -> inp f16 [t][y][x][ci]} + {prep -> wB,bR} + {nearfar}
//   conv_mfma : part[p] f32 = quarter-K conv via v_mfma_f32_16x16x32_f16
//               2880 blocks = (p, t, y-pair, xseg); LDS single-buffer 26KB, ONE barrier;
//               r5's staging/swizzle verbatim. K-split x4 lifts occupancy 1.5->~5.6 w/SIMD
//               (r8/r9 LDS-free: MfmaUtil 2.7%, latency-bound at 1.6 w/SIMD -> reverted)
//   combine   : fld = sum of 4 partials + bias
//   pack      : fld -> cellp, cells stored as (lo, hi-lo) half2 pairs
//   render    : 8 lanes/ray x 16 samples, grid-space march, log2 optics,
//               exec-masked cached cell reload

struct __align__(16) Cell { __half2 h0, h1, h2, h3; };

typedef __attribute__((ext_vector_type(4))) float     f32x4;
typedef __attribute__((ext_vector_type(8))) _Float16  f16x8;

__device__ __forceinline__ float fexp2(float x) { return __builtin_amdgcn_exp2f(x); }   // v_exp_f32
__device__ __forceinline__ float flog2(float x) { return __builtin_amdgcn_logf(x); }    // v_log_f32

// blocks [0,480): transpose | [480,696): weight prep | [696,1336): nearfar
__global__ __launch_bounds__(256) void setup_kernel(
        const float* __restrict__ xin, __half* __restrict__ inp,
        const float* __restrict__ w, const float* __restrict__ cb,
        const float* __restrict__ dw, __half* __restrict__ wB, float* __restrict__ bR,
        const float* __restrict__ ro, const float* __restrict__ rd,
        float* __restrict__ nearA, float* __restrict__ farA) {
    int b = blockIdx.x;
    if (b < 480) {
        // ---- transpose: inp[((t*96+y)*96+x)*128 + f*16+z] = (half) vol[f][t][z][y][x]
        __shared__ __half lds[96 * 136];
        int t = b / 96, y = b - (b / 96) * 96;
        for (int i = threadIdx.x; i < 12288; i += 256) {
            int row = i / 96;
            int x   = i - row * 96;
            int f = row >> 4, z = row & 15;
            float v = xin[(((size_t)(f * 5 + t) * 16 + z) * 96 + y) * 96 + x];
            lds[x * 136 + row] = __float2half(v);
        }
        __syncthreads();
        __half* ob = inp + ((size_t)(t * 96 + y) * 96) * 128;
        for (int c = threadIdx.x; c < 1536; c += 256) {
            int x = c >> 4, sub = c & 15;
            uint4 v = *(const uint4*)(lds + x * 136 + sub * 8);
            *(uint4*)(ob + (size_t)x * 128 + sub * 8) = v;
        }
    } else if (b < 696) {
        // ---- weight prep: wB[((p*27+tap)*16+zo)*32+cs], ci = p*32+cs
        int i = (b - 480) * 256 + threadIdx.x;       // 0 .. 55295 exactly
        if (i < 16) {
            float s = 0.f;
            #pragma unroll
            for (int f = 0; f < 8; ++f) s += cb[f * 16 + i] * dw[f];
            bR[i] = s;
        }
        int cs  = i & 31;
        int zo  = (i >> 5) & 15;
        int pt  = i >> 9;
        int p   = pt / 27;
        int tap = pt - p * 27;
        int ci  = p * 32 + cs;
        float s = 0.f;
        #pragma unroll
        for (int f = 0; f < 8; ++f)
            s += w[(size_t)((f * 16 + zo) * 128 + ci) * 27 + tap] * dw[f];
        wB[i] = __float2half(s);
    } else {
        // ---- nearfar: per-ray near/far only
        int gid = (b - 696) * 256 + threadIdx.x;     // 0 .. 163839
        const float* o = ro + (size_t)gid * 3;
        const float* d = rd + (size_t)gid * 3;
        float ox = o[0], oy = o[1], oz = o[2];
        float dx = d[0], dy = d[1], dz = d[2];
        float t1x = (0.f - ox) / dx, t2x = (1.f - ox) / dx;
        float t1y = (0.f - oy) / dy, t2y = (1.f - oy) / dy;
        float t1z = (0.f - oz) / dz, t2z = (1.f - oz) / dz;
        float nr = fmaxf(fmaxf(fminf(t1x, t2x), fminf(t1y, t2y)), fminf(t1z, t2z));
        float fr = fminf(fminf(fmaxf(t1x, t2x), fmaxf(t1y, t2y)), fmaxf(t1z, t2z));
        nr = fmaxf(nr, 0.01f);
        fr = fmaxf(fr, nr + 1e-6f);
        nearA[gid] = nr;
        farA[gid]  = fr;
    }
}

// Block = (p, t, y-pair, 32-x seg): 2880 = 4p x 5t x 48yp x 3xs. 128 thr = 2 waves;
// wave w -> y = y0+w, two 16-x tiles (acc0/acc1), 27 taps of ci-quarter p.
// LDS: ONE buffer [12 rows][34 x][4 slots of 8 halves], slot s' = sub ^ ((xl>>1)&3)
// (bank-conflict-free ds_read_b128, verified swizzle from r5). Single barrier.
// Output: f32 partial to part[p]; combine sums 4 partials + bias.
__global__ __launch_bounds__(128) void conv_mfma_kernel(
        const __half* __restrict__ inp, const __half* __restrict__ wB,
        float* __restrict__ part) {
    int bid = blockIdx.x;
    int wg  = (bid & 7) * 360 + (bid >> 3);      // bijective XCD swizzle (2880 = 8*360)
    int p   = wg & 3;
    int wq  = wg >> 2;                           // 0..719
    int xs  = wq % 3;
    int rem = wq / 3;
    int yp  = rem % 48;
    int t   = rem / 48;
    int xseg = xs * 32, y0 = yp * 2;

    __shared__ __half lds[12 * 34 * 32];             // 26,112 B, single buffer
    const int w    = threadIdx.x >> 6;
    const int lane = threadIdx.x & 63;
    const int l15  = lane & 15;
    const int ksub = lane >> 4;

    // ---- main staging columns: 128 lanes x 12 rows (xl 0..31, sub 0..3) ----
    const int xl0 = threadIdx.x >> 2, sub0 = threadIdx.x & 3;
    const int xg0 = xseg + xl0 - 1;
    const bool xok0 = (unsigned)xg0 < 96u;
    const int glo0 = xg0 * 128 + sub0 * 8 + (p << 5);            // halves
    const int lof0 = xl0 * 32 + ((sub0 ^ ((xl0 >> 1) & 3)) << 3);
    // ---- halo: 96 chunks (xl 32..33, sub 0..3, rows 0..11) -> lanes 0..95, 1 each ----
    const int q    = threadIdx.x / 12;                           // 0..10
    const int rowh = threadIdx.x - q * 12;                       // 0..11
    const int xl1  = 32 + (q >> 2), sub1 = q & 3;
    const int xg1  = xseg + xl1 - 1;
    const bool hwr = (q < 8);
    const bool hld = hwr && ((unsigned)xg1 < 96u);
    const int glo1 = xg1 * 128 + sub1 * 8 + (p << 5);
    const int lof1 = xl1 * 32 + ((sub1 ^ ((xl1 >> 1) & 3)) << 3);

    // ---- swizzled B-fragment read offsets (halves) ----
    int offA[3];
    #pragma unroll
    for (int kx = 0; kx < 3; ++kx) {
        int X = l15 + kx;
        offA[kx] = X * 32 + ((ksub ^ ((X >> 1) & 3)) << 3);      // tile B = +512
    }

    // ---- stage (issue all loads, then commit to LDS, one barrier) ----
    uint4 vm[12];
    #pragma unroll
    for (int r = 0; r < 12; ++r) {
        int tt = t + (r >> 2) - 1;
        int yy = y0 + (r & 3) - 1;
        bool rok = ((unsigned)tt < 5u) & ((unsigned)yy < 96u);
        int rbase = (tt * 96 + yy) * 12288;
        uint4 v = {0u, 0u, 0u, 0u};
        if (rok & xok0) v = *(const uint4*)(inp + rbase + glo0);
        vm[r] = v;
    }
    uint4 vh = {0u, 0u, 0u, 0u};
    {
        int tt = t + (rowh >> 2) - 1;
        int yy = y0 + (rowh & 3) - 1;
        bool rok = ((unsigned)tt < 5u) & ((unsigned)yy < 96u);
        int rbase = (tt * 96 + yy) * 12288;
        if (rok & hld) vh = *(const uint4*)(inp + rbase + glo1);
    }
    #pragma unroll
    for (int r = 0; r < 12; ++r)
        *(uint4*)(lds + r * 1088 + lof0) = vm[r];
    if (hwr)
        *(uint4*)(lds + rowh * 1088 + lof1) = vh;
    __syncthreads();

    // ---- compute: 27 taps x (1 L1 weight load + 2 ds_read_b128 + 2 MFMA) ----
    f32x4 acc0 = {0.f, 0.f, 0.f, 0.f};
    f32x4 acc1 = {0.f, 0.f, 0.f, 0.f};
    const __half* wp_base = wB + (size_t)p * 13824 + l15 * 32 + ksub * 8;
    #pragma unroll
    for (int kt = 0; kt < 3; ++kt) {
        #pragma unroll
        for (int ky = 0; ky < 3; ++ky) {
            const __half* lrow = lds + (kt * 4 + w + ky) * 1088;
            #pragma unroll
            for (int kx = 0; kx < 3; ++kx) {
                int tap = (kt * 3 + ky) * 3 + kx;
                f16x8 aw = *(const f16x8*)(wp_base + tap * 512);
                f16x8 b0 = *(const f16x8*)(lrow + offA[kx]);
                acc0 = __builtin_amdgcn_mfma_f32_16x16x32_f16(aw, b0, acc0, 0, 0, 0);
                f16x8 b1 = *(const f16x8*)(lrow + offA[kx] + 512);
                acc1 = __builtin_amdgcn_mfma_f32_16x16x32_f16(aw, b1, acc1, 0, 0, 0);
            }
        }
    }

    // ---- epilogue: partial store, D[row=zo=(ksub*4+r)][col=x=l15] ----
    int yw = y0 + w;
    float* po = part + (size_t)p * 737280;
    #pragma unroll
    for (int r = 0; r < 4; ++r) {
        int zo = ksub * 4 + r;
        size_t o = (((size_t)t * 16 + zo) * 96 + yw) * 96 + xseg + l15;
        po[o]      = acc0[r];
        po[o + 16] = acc1[r];
    }
}

// fld = part[0..3] summed + bias[z]. 184320 float4 groups.
__global__ __launch_bounds__(256) void combine_kernel(
        const float* __restrict__ part, const float* __restrict__ bR,
        float* __restrict__ fld) {
    int i = blockIdx.x * 256 + threadIdx.x;
    if (i >= 184320) return;
    int z = (i / 2304) & 15;
    float b = bR[z];
    float4 r = make_float4(b, b, b, b);
    const float4* pp = (const float4*)part;
    #pragma unroll
    for (int s = 0; s < 4; ++s) {
        float4 a = pp[(size_t)s * 184320 + i];
        r.x += a.x; r.y += a.y; r.z += a.z; r.w += a.w;
    }
    ((float4*)fld)[i] = r;
}

// cellp[t][z][y][x]: 4 half2 of (lo, hi-lo) along x for the 4 (z,y) corner rows.
__global__ __launch_bounds__(256) void pack_kernel(
        const float* __restrict__ fld, Cell* __restrict__ cellp) {
    int i = blockIdx.x * 256 + threadIdx.x;
    if (i >= 737280) return;
    int x = i % 96;
    int r = i / 96;
    int y = r % 96;
    int r2 = r / 96;
    int z = r2 % 16;
    int t = r2 / 16;
    const float* ft = fld + (size_t)t * 147456;
    int xp = min(x + 1, 95);
    int yr0 = y * 96, yr1 = min(y + 1, 95) * 96;
    int zr0 = z * 9216, zr1 = min(z + 1, 15) * 9216;
    float c000 = ft[zr0 + yr0 + x], c001 = ft[zr0 + yr0 + xp];
    float c010 = ft[zr0 + yr1 + x], c011 = ft[zr0 + yr1 + xp];
    float c100 = ft[zr1 + yr0 + x], c101 = ft[zr1 + yr0 + xp];
    float c110 = ft[zr1 + yr1 + x], c111 = ft[zr1 + yr1 + xp];
    Cell cl;
    cl.h0 = __floats2half2_rn(c000, c001 - c000);
    cl.h1 = __floats2half2_rn(c010, c011 - c010);
    cl.h2 = __floats2half2_rn(c100, c101 - c100);
    cl.h3 = __floats2half2_rn(c110, c111 - c110);
    cellp[i] = cl;
}

// 8 lanes per ray, 16 samples each. Grid-space march; log2-domain optics;
// exec-masked cached cell reload (proven-minimal gather shape).
__global__ __launch_bounds__(256) void render_kernel(
        const float* __restrict__ ro, const float* __restrict__ rd,
        const Cell* __restrict__ cellp,
        const float* __restrict__ nearA, const float* __restrict__ farA,
        const float* __restrict__ dens_b, float* __restrict__ out) {
    int b = blockIdx.x;                 // 0..5119
    int b7 = b & 7, bhi = b >> 3;       // bhi 0..639
    int t, seg;
    if (b7 < 5) { t = b7; seg = bhi; }                       // XCD 0..4: one t each
    else { int j = (b7 - 5) * 640 + bhi; t = j / 384; seg = 640 + j % 384; }
    int c = threadIdx.x & 7;
    int ray = t * NRAYS + seg * 32 + (threadIdx.x >> 3);

    const float* o = ro + (size_t)ray * 3;
    const float* d = rd + (size_t)ray * 3;
    float ox = o[0], oy = o[1], oz = o[2];
    float dx = d[0], dy = d[1], dz = d[2];
    float nr = nearA[ray], fr = farA[ray];
    const Cell* vt = cellp + (size_t)t * 147456;
    const float L2E = 1.4426950408889634f;
    float db2 = dens_b[0] * L2E;

    float span = fr - nr;
    float step = span * 0.0078125f;
    float s  = fmaf((float)(c * 16), step, nr);
    float mid = s + 0.5f * step;
    float pxg = fmaf(dx, mid, ox) * 95.f;
    float pyg = fmaf(dy, mid, oy) * 95.f;
    float pzg = fmaf(dz, mid, oz) * 15.f;
    float ddxg = dx * step * 95.f, ddyg = dy * step * 95.f, ddzg = dz * step * 15.f;

    float num = 0.f, den = 0.f, A2 = 0.f;
    float trans = 1.f;
    int pidx = -1;
    Cell cl;
    for (int kk = 0; kk < 16; ++kk) {
        // consumed samples are in-box -> int clamps suffice (fracs identical)
        int x0 = min(max((int)pxg, 0), 94);
        int y0 = min(max((int)pyg, 0), 94);
        int z0 = min(max((int)pzg, 0), 14);
        float fx = pxg - (float)x0, fy = pyg - (float)y0, fz = pzg - (float)z0;

        int idx = z0 * 9216 + y0 * 96 + x0;
        if (idx != pidx) {                 // exec-masked 16B gather, changed lanes only
            pidx = idx;
            cl = vt[idx];
        }

        // (lo, hi-lo) packed cells -> v_fma_mix lerps
        float v00 = fmaf(fx, __half2float(__high2half(cl.h0)), __half2float(__low2half(cl.h0)));
        float v01 = fmaf(fx, __half2float(__high2half(cl.h1)), __half2float(__low2half(cl.h1)));
        float v10 = fmaf(fx, __half2float(__high2half(cl.h2)), __half2float(__low2half(cl.h2)));
        float v11 = fmaf(fx, __half2float(__high2half(cl.h3)), __half2float(__low2half(cl.h3)));
        float v0  = fmaf(fy, v01 - v00, v00);
        float v1  = fmaf(fy, v11 - v10, v10);
        float pre2 = fmaf(fmaf(fz, v1 - v0, v0), L2E, db2);      // (pre+db)*log2e

        float u = fexp2(-fabsf(pre2));
        float dens2 = fmaxf(pre2, 0.f) + flog2(1.f + u);         // softplus * log2e
        float dd2 = dens2 * step;                                 // dd * log2e
        float ex = fexp2(-dd2);                                   // exp(-dd)
        float wgt = (1.f - ex) * trans;
        num = fmaf(wgt, s, num);
        den += wgt;
        trans *= ex;
        A2 += dd2;
        s += step; pxg += ddxg; pyg += ddyg; pzg += ddzg;
    }
    // prefix transmittance across the 8 chunks of this ray
    int lane = threadIdx.x & 63;
    int qb = lane & ~7;
    float P = 0.f;
    #pragma unroll
    for (int j = 0; j < 7; ++j) {
        float Aj = __shfl(A2, qb + j, 64);
        P += (c > j) ? Aj : 0.f;
    }
    float sc = fexp2(-P);
    float numc = num * sc;
    float denc = den * sc;
    numc += __shfl_xor(numc, 1, 64);
    numc += __shfl_xor(numc, 2, 64);
    numc += __shfl_xor(numc, 4, 64);
    denc += __shfl_xor(denc, 1, 64);
    denc += __shfl_xor(denc, 2, 64);
    denc += __shfl_xor(denc, 4, 64);
    if (c == 0) {
        float depth = numc / (denc + 1e-10f);
        // per-ray clamp [near, s_last]; equals ref's global clamp to ~1e-8
        float slast = fmaf(0.9921875f, span, nr);
        depth = fminf(fmaxf(depth, nr), slast);
        out[ray] = depth;
    }
}

extern "C" void kernel_launch(void* const* d_in, const int* in_sizes, int n_in,
                              void* d_out, int out_size, void* d_ws, size_t ws_size,
                              hipStream_t stream) {
    const float* vol = (const float*)d_in[0];
    const float* ro  = (const float*)d_in[1];
    const float* rd  = (const float*)d_in[2];
    const float* cw  = (const float*)d_in[3];
    const float* cb  = (const float*)d_in[4];
    const float* dw  = (const float*)d_in[5];
    const float* dbp = (const float*)d_in[6];
    float* out = (float*)d_out;

    float* ws      = (float*)d_ws;
    float* fld     = ws;                                    // [0 .. 737,280)
    __half* inp    = (__half*)(ws + 737280);                // 5,898,240 halves
    Cell*  cellp   = (Cell*)(ws + 737280);                  // overlaps dead inp
    __half* wB     = (__half*)(ws + 737280 + 2949120);      // 55,296 halves
    float* bR      = ws + 737280 + 2949120 + 27648;         // 16 (+pad to 32)
    float* nearA   = bR + 32;                               // 163,840
    float* farA    = nearA + 163840;                        // 163,840
    float* part    = farA + 163840;                         // 4 x 737,280

    hipLaunchKernelGGL(setup_kernel, dim3(1336), dim3(256), 0, stream,
                       vol, inp, cw, cb, dw, wB, bR, ro, rd, nearA, farA);
    hipLaunchKernelGGL(conv_mfma_kernel, dim3(2880), dim3(128), 0, stream,
                       inp, wB, part);
    hipLaunchKernelGGL(combine_kernel, dim3(720), dim3(256), 0, stream,
                       part, bR, fld);
    hipLaunchKernelGGL(pack_kernel, dim3(2880), dim3(256), 0, stream, fld, cellp);
    hipLaunchKernelGGL(render_kernel, dim3(5120), dim3(256), 0, stream,
                       ro, rd, cellp, nearA, farA, dbp, out);
}

// Round 11
// 156.994 us; speedup vs baseline: 1.2466x; 1.0254x over previous
//
#include <hip/hip_runtime.h>
#include <hip/hip_fp16.h>
#include <cstdint>
#include <cstddef>

#define T_DIM 5
#define F_DIM 8
#define Z_DIM 16
#define Y_DIM 96
#define X_DIM 96
#define NRAYS 32768
#define K_SAMP 128

// Pipeline (4 launches):
//   setup     : fused {transpose -> inp f16 [t][y][x][ci]} + {prep -> wB,bR} + {nearfar}
//   conv_mfma : part[p] f32 = quarter-K conv via v_mfma_f32_16x16x32_f16
//               2880 blocks = (p, t, y-pair, xseg); LDS single-buffer 26KB, ONE barrier
//   combpack  : fused {sum 4 partials + bias} + {pack cells} via 6.9KB LDS tile
//               (removes combine launch, fld round-trip, and pack's 8x L2 refetch)
//   render    : 8 lanes/ray x 16 samples, grid-space march, log2 optics,
//               exec-masked cached cell reload

struct __align__(16) Cell { __half2 h0, h1, h2, h3; };

typedef __attribute__((ext_vector_type(4))) float     f32x4;
typedef __attribute__((ext_vector_type(8))) _Float16  f16x8;

__device__ __forceinline__ float fexp2(float x) { return __builtin_amdgcn_exp2f(x); }   // v_exp_f32
__device__ __forceinline__ float flog2(float x) { return __builtin_amdgcn_logf(x); }    // v_log_f32

// blocks [0,480): transpose | [480,696): weight prep | [696,1336): nearfar
__global__ __launch_bounds__(256) void setup_kernel(
        const float* __restrict__ xin, __half* __restrict__ inp,
        const float* __restrict__ w, const float* __restrict__ cb,
        const float* __restrict__ dw, __half* __restrict__ wB, float* __restrict__ bR,
        const float* __restrict__ ro, const float* __restrict__ rd,
        float* __restrict__ nearA, float* __restrict__ farA) {
    int b = blockIdx.x;
    if (b < 480) {
        // ---- transpose: inp[((t*96+y)*96+x)*128 + f*16+z] = (half) vol[f][t][z][y][x]
        __shared__ __half lds[96 * 136];
        int t = b / 96, y = b - (b / 96) * 96;
        for (int i = threadIdx.x; i < 12288; i += 256) {
            int row = i / 96;
            int x   = i - row * 96;
            int f = row >> 4, z = row & 15;
            float v = xin[(((size_t)(f * 5 + t) * 16 + z) * 96 + y) * 96 + x];
            lds[x * 136 + row] = __float2half(v);
        }
        __syncthreads();
        __half* ob = inp + ((size_t)(t * 96 + y) * 96) * 128;
        for (int c = threadIdx.x; c < 1536; c += 256) {
            int x = c >> 4, sub = c & 15;
            uint4 v = *(const uint4*)(lds + x * 136 + sub * 8);
            *(uint4*)(ob + (size_t)x * 128 + sub * 8) = v;
        }
    } else if (b < 696) {
        // ---- weight prep: wB[((p*27+tap)*16+zo)*32+cs], ci = p*32+cs
        int i = (b - 480) * 256 + threadIdx.x;       // 0 .. 55295 exactly
        if (i < 16) {
            float s = 0.f;
            #pragma unroll
            for (int f = 0; f < 8; ++f) s += cb[f * 16 + i] * dw[f];
            bR[i] = s;
        }
        int cs  = i & 31;
        int zo  = (i >> 5) & 15;
        int pt  = i >> 9;
        int p   = pt / 27;
        int tap = pt - p * 27;
        int ci  = p * 32 + cs;
        float s = 0.f;
        #pragma unroll
        for (int f = 0; f < 8; ++f)
            s += w[(size_t)((f * 16 + zo) * 128 + ci) * 27 + tap] * dw[f];
        wB[i] = __float2half(s);
    } else {
        // ---- nearfar: per-ray near/far only
        int gid = (b - 696) * 256 + threadIdx.x;     // 0 .. 163839
        const float* o = ro + (size_t)gid * 3;
        const float* d = rd + (size_t)gid * 3;
        float ox = o[0], oy = o[1], oz = o[2];
        float dx = d[0], dy = d[1], dz = d[2];
        float t1x = (0.f - ox) / dx, t2x = (1.f - ox) / dx;
        float t1y = (0.f - oy) / dy, t2y = (1.f - oy) / dy;
        float t1z = (0.f - oz) / dz, t2z = (1.f - oz) / dz;
        float nr = fmaxf(fmaxf(fminf(t1x, t2x), fminf(t1y, t2y)), fminf(t1z, t2z));
        float fr = fminf(fminf(fmaxf(t1x, t2x), fmaxf(t1y, t2y)), fmaxf(t1z, t2z));
        nr = fmaxf(nr, 0.01f);
        fr = fmaxf(fr, nr + 1e-6f);
        nearA[gid] = nr;
        farA[gid]  = fr;
    }
}

// Block = (p, t, y-pair, 32-x seg): 2880 = 4p x 5t x 48yp x 3xs. 128 thr = 2 waves;
// wave w -> y = y0+w, two 16-x tiles (acc0/acc1), 27 taps of ci-quarter p.
// LDS: ONE buffer [12 rows][34 x][4 slots of 8 halves], slot s' = sub ^ ((xl>>1)&3)
// (bank-conflict-free ds_read_b128). Single barrier. f32 partial out to part[p].
__global__ __launch_bounds__(128) void conv_mfma_kernel(
        const __half* __restrict__ inp, const __half* __restrict__ wB,
        float* __restrict__ part) {
    int bid = blockIdx.x;
    int wg  = (bid & 7) * 360 + (bid >> 3);      // bijective XCD swizzle (2880 = 8*360)
    int p   = wg & 3;
    int wq  = wg >> 2;                           // 0..719
    int xs  = wq % 3;
    int rem = wq / 3;
    int yp  = rem % 48;
    int t   = rem / 48;
    int xseg = xs * 32, y0 = yp * 2;

    __shared__ __half lds[12 * 34 * 32];             // 26,112 B, single buffer
    const int w    = threadIdx.x >> 6;
    const int lane = threadIdx.x & 63;
    const int l15  = lane & 15;
    const int ksub = lane >> 4;

    // ---- main staging columns: 128 lanes x 12 rows (xl 0..31, sub 0..3) ----
    const int xl0 = threadIdx.x >> 2, sub0 = threadIdx.x & 3;
    const int xg0 = xseg + xl0 - 1;
    const bool xok0 = (unsigned)xg0 < 96u;
    const int glo0 = xg0 * 128 + sub0 * 8 + (p << 5);            // halves
    const int lof0 = xl0 * 32 + ((sub0 ^ ((xl0 >> 1) & 3)) << 3);
    // ---- halo: 96 chunks (xl 32..33, sub 0..3, rows 0..11) -> lanes 0..95, 1 each ----
    const int q    = threadIdx.x / 12;                           // 0..10
    const int rowh = threadIdx.x - q * 12;                       // 0..11
    const int xl1  = 32 + (q >> 2), sub1 = q & 3;
    const int xg1  = xseg + xl1 - 1;
    const bool hwr = (q < 8);
    const bool hld = hwr && ((unsigned)xg1 < 96u);
    const int glo1 = xg1 * 128 + sub1 * 8 + (p << 5);
    const int lof1 = xl1 * 32 + ((sub1 ^ ((xl1 >> 1) & 3)) << 3);

    // ---- swizzled B-fragment read offsets (halves) ----
    int offA[3];
    #pragma unroll
    for (int kx = 0; kx < 3; ++kx) {
        int X = l15 + kx;
        offA[kx] = X * 32 + ((ksub ^ ((X >> 1) & 3)) << 3);      // tile B = +512
    }

    // ---- stage (issue all loads, then commit to LDS, one barrier) ----
    uint4 vm[12];
    #pragma unroll
    for (int r = 0; r < 12; ++r) {
        int tt = t + (r >> 2) - 1;
        int yy = y0 + (r & 3) - 1;
        bool rok = ((unsigned)tt < 5u) & ((unsigned)yy < 96u);
        int rbase = (tt * 96 + yy) * 12288;
        uint4 v = {0u, 0u, 0u, 0u};
        if (rok & xok0) v = *(const uint4*)(inp + rbase + glo0);
        vm[r] = v;
    }
    uint4 vh = {0u, 0u, 0u, 0u};
    {
        int tt = t + (rowh >> 2) - 1;
        int yy = y0 + (rowh & 3) - 1;
        bool rok = ((unsigned)tt < 5u) & ((unsigned)yy < 96u);
        int rbase = (tt * 96 + yy) * 12288;
        if (rok & hld) vh = *(const uint4*)(inp + rbase + glo1);
    }
    #pragma unroll
    for (int r = 0; r < 12; ++r)
        *(uint4*)(lds + r * 1088 + lof0) = vm[r];
    if (hwr)
        *(uint4*)(lds + rowh * 1088 + lof1) = vh;
    __syncthreads();

    // ---- compute: 27 taps x (1 L1 weight load + 2 ds_read_b128 + 2 MFMA) ----
    f32x4 acc0 = {0.f, 0.f, 0.f, 0.f};
    f32x4 acc1 = {0.f, 0.f, 0.f, 0.f};
    const __half* wp_base = wB + (size_t)p * 13824 + l15 * 32 + ksub * 8;
    #pragma unroll
    for (int kt = 0; kt < 3; ++kt) {
        #pragma unroll
        for (int ky = 0; ky < 3; ++ky) {
            const __half* lrow = lds + (kt * 4 + w + ky) * 1088;
            #pragma unroll
            for (int kx = 0; kx < 3; ++kx) {
                int tap = (kt * 3 + ky) * 3 + kx;
                f16x8 aw = *(const f16x8*)(wp_base + tap * 512);
                f16x8 b0 = *(const f16x8*)(lrow + offA[kx]);
                acc0 = __builtin_amdgcn_mfma_f32_16x16x32_f16(aw, b0, acc0, 0, 0, 0);
                f16x8 b1 = *(const f16x8*)(lrow + offA[kx] + 512);
                acc1 = __builtin_amdgcn_mfma_f32_16x16x32_f16(aw, b1, acc1, 0, 0, 0);
            }
        }
    }

    // ---- epilogue: partial store, D[row=zo=(ksub*4+r)][col=x=l15] ----
    int yw = y0 + w;
    float* po = part + (size_t)p * 737280;
    #pragma unroll
    for (int r = 0; r < 4; ++r) {
        int zo = ksub * 4 + r;
        size_t o = (((size_t)t * 16 + zo) * 96 + yw) * 96 + xseg + l15;
        po[o]      = acc0[r];
        po[o + 16] = acc1[r];
    }
}

// Fused combine+pack. Block = (t, z, 8-y tile): 960 = 5t x 16z x 12yt.
// Stage: 2 z-planes x 9 y-rows x 96 x of field (sum 4 partials + bias, same order
// as the old combine -> bitwise-identical) into 6.9KB LDS, edge rows clamped.
// Pack: 768 cells/block (3/thread) from LDS, stride-1 conflict-free reads.
__global__ __launch_bounds__(256) void combpack_kernel(
        const float* __restrict__ part, const float* __restrict__ bR,
        Cell* __restrict__ cellp) {
    int b = blockIdx.x;                          // 0..959
    int t = b / 192;
    int r = b - t * 192;
    int z = r / 12;
    int y0 = (r - z * 12) * 8;
    int z1 = min(z + 1, 15);

    __shared__ float Lf[18 * 96];                // rows 0..8: plane z; 9..17: plane z+1
    const float4* pp = (const float4*)part;
    for (int j = threadIdx.x; j < 432; j += 256) {       // 18 rows x 24 float4
        int row = j / 24, xq = j - row * 24;
        int plane = row >= 9;
        int zz = plane ? z1 : z;
        int yy = min(y0 + row - (plane ? 9 : 0), 95);
        size_t f4 = ((size_t)(t * 16 + zz) * 96 + yy) * 24 + xq;
        float bz = bR[zz];
        float4 a0 = pp[f4];
        float4 a1 = pp[f4 + 184320];
        float4 a2 = pp[f4 + 2 * 184320];
        float4 a3 = pp[f4 + 3 * 184320];
        float4 s;
        s.x = bz + a0.x + a1.x + a2.x + a3.x;
        s.y = bz + a0.y + a1.y + a2.y + a3.y;
        s.z = bz + a0.z + a1.z + a2.z + a3.z;
        s.w = bz + a0.w + a1.w + a2.w + a3.w;
        *(float4*)(Lf + row * 96 + xq * 4) = s;
    }
    __syncthreads();

    const size_t tz = (size_t)(t * 16 + z);
    #pragma unroll
    for (int k = 0; k < 3; ++k) {
        int c = threadIdx.x + k * 256;           // 0..767
        int yl = c / 96, x = c - yl * 96;
        int xp = min(x + 1, 95);
        float c000 = Lf[yl * 96 + x],        c001 = Lf[yl * 96 + xp];
        float c010 = Lf[(yl + 1) * 96 + x],  c011 = Lf[(yl + 1) * 96 + xp];
        float c100 = Lf[(9 + yl) * 96 + x],  c101 = Lf[(9 + yl) * 96 + xp];
        float c110 = Lf[(10 + yl) * 96 + x], c111 = Lf[(10 + yl) * 96 + xp];
        Cell cl;
        cl.h0 = __floats2half2_rn(c000, c001 - c000);
        cl.h1 = __floats2half2_rn(c010, c011 - c010);
        cl.h2 = __floats2half2_rn(c100, c101 - c100);
        cl.h3 = __floats2half2_rn(c110, c111 - c110);
        cellp[(tz * 96 + y0 + yl) * 96 + x] = cl;
    }
}

// 8 lanes per ray, 16 samples each. Grid-space march; log2-domain optics;
// exec-masked cached cell reload (proven-minimal gather shape).
__global__ __launch_bounds__(256) void render_kernel(
        const float* __restrict__ ro, const float* __restrict__ rd,
        const Cell* __restrict__ cellp,
        const float* __restrict__ nearA, const float* __restrict__ farA,
        const float* __restrict__ dens_b, float* __restrict__ out) {
    int b = blockIdx.x;                 // 0..5119
    int b7 = b & 7, bhi = b >> 3;       // bhi 0..639
    int t, seg;
    if (b7 < 5) { t = b7; seg = bhi; }                       // XCD 0..4: one t each
    else { int j = (b7 - 5) * 640 + bhi; t = j / 384; seg = 640 + j % 384; }
    int c = threadIdx.x & 7;
    int ray = t * NRAYS + seg * 32 + (threadIdx.x >> 3);

    const float* o = ro + (size_t)ray * 3;
    const float* d = rd + (size_t)ray * 3;
    float ox = o[0], oy = o[1], oz = o[2];
    float dx = d[0], dy = d[1], dz = d[2];
    float nr = nearA[ray], fr = farA[ray];
    const Cell* vt = cellp + (size_t)t * 147456;
    const float L2E = 1.4426950408889634f;
    float db2 = dens_b[0] * L2E;

    float span = fr - nr;
    float step = span * 0.0078125f;
    float s  = fmaf((float)(c * 16), step, nr);
    float mid = s + 0.5f * step;
    float pxg = fmaf(dx, mid, ox) * 95.f;
    float pyg = fmaf(dy, mid, oy) * 95.f;
    float pzg = fmaf(dz, mid, oz) * 15.f;
    float ddxg = dx * step * 95.f, ddyg = dy * step * 95.f, ddzg = dz * step * 15.f;

    float num = 0.f, den = 0.f, A2 = 0.f;
    float trans = 1.f;
    int pidx = -1;
    Cell cl;
    for (int kk = 0; kk < 16; ++kk) {
        // consumed samples are in-box -> int clamps suffice (fracs identical)
        int x0 = min(max((int)pxg, 0), 94);
        int y0 = min(max((int)pyg, 0), 94);
        int z0 = min(max((int)pzg, 0), 14);
        float fx = pxg - (float)x0, fy = pyg - (float)y0, fz = pzg - (float)z0;

        int idx = z0 * 9216 + y0 * 96 + x0;
        if (idx != pidx) {                 // exec-masked 16B gather, changed lanes only
            pidx = idx;
            cl = vt[idx];
        }

        // (lo, hi-lo) packed cells -> v_fma_mix lerps
        float v00 = fmaf(fx, __half2float(__high2half(cl.h0)), __half2float(__low2half(cl.h0)));
        float v01 = fmaf(fx, __half2float(__high2half(cl.h1)), __half2float(__low2half(cl.h1)));
        float v10 = fmaf(fx, __half2float(__high2half(cl.h2)), __half2float(__low2half(cl.h2)));
        float v11 = fmaf(fx, __half2float(__high2half(cl.h3)), __half2float(__low2half(cl.h3)));
        float v0  = fmaf(fy, v01 - v00, v00);
        float v1  = fmaf(fy, v11 - v10, v10);
        float pre2 = fmaf(fmaf(fz, v1 - v0, v0), L2E, db2);      // (pre+db)*log2e

        float u = fexp2(-fabsf(pre2));
        float dens2 = fmaxf(pre2, 0.f) + flog2(1.f + u);         // softplus * log2e
        float dd2 = dens2 * step;                                 // dd * log2e
        float ex = fexp2(-dd2);                                   // exp(-dd)
        float wgt = (1.f - ex) * trans;
        num = fmaf(wgt, s, num);
        den += wgt;
        trans *= ex;
        A2 += dd2;
        s += step; pxg += ddxg; pyg += ddyg; pzg += ddzg;
    }
    // prefix transmittance across the 8 chunks of this ray
    int lane = threadIdx.x & 63;
    int qb = lane & ~7;
    float P = 0.f;
    #pragma unroll
    for (int j = 0; j < 7; ++j) {
        float Aj = __shfl(A2, qb + j, 64);
        P += (c > j) ? Aj : 0.f;
    }
    float sc = fexp2(-P);
    float numc = num * sc;
    float denc = den * sc;
    numc += __shfl_xor(numc, 1, 64);
    numc += __shfl_xor(numc, 2, 64);
    numc += __shfl_xor(numc, 4, 64);
    denc += __shfl_xor(denc, 1, 64);
    denc += __shfl_xor(denc, 2, 64);
    denc += __shfl_xor(denc, 4, 64);
    if (c == 0) {
        float depth = numc / (denc + 1e-10f);
        // per-ray clamp [near, s_last]; equals ref's global clamp to ~1e-8
        float slast = fmaf(0.9921875f, span, nr);
        depth = fminf(fmaxf(depth, nr), slast);
        out[ray] = depth;
    }
}

extern "C" void kernel_launch(void* const* d_in, const int* in_sizes, int n_in,
                              void* d_out, int out_size, void* d_ws, size_t ws_size,
                              hipStream_t stream) {
    const float* vol = (const float*)d_in[0];
    const float* ro  = (const float*)d_in[1];
    const float* rd  = (const float*)d_in[2];
    const float* cw  = (const float*)d_in[3];
    const float* cb  = (const float*)d_in[4];
    const float* dw  = (const float*)d_in[5];
    const float* dbp = (const float*)d_in[6];
    float* out = (float*)d_out;

    float* ws      = (float*)d_ws;
    __half* inp    = (__half*)(ws + 737280);                // 5,898,240 halves
    Cell*  cellp   = (Cell*)(ws + 737280);                  // overlaps dead inp
    __half* wB     = (__half*)(ws + 737280 + 2949120);      // 55,296 halves
    float* bR      = ws + 737280 + 2949120 + 27648;         // 16 (+pad to 32)
    float* nearA   = bR + 32;                               // 163,840
    float* farA    = nearA + 163840;                        // 163,840
    float* part    = farA + 163840;                         // 4 x 737,280

    hipLaunchKernelGGL(setup_kernel, dim3(1336), dim3(256), 0, stream,
                       vol, inp, cw, cb, dw, wB, bR, ro, rd, nearA, farA);
    hipLaunchKernelGGL(conv_mfma_kernel, dim3(2880), dim3(128), 0, stream,
                       inp, wB, part);
    hipLaunchKernelGGL(combpack_kernel, dim3(960), dim3(256), 0, stream,
                       part, bR, cellp);
    hipLaunchKernelGGL(render_kernel, dim3(5120), dim3(256), 0, stream,
                       ro, rd, cellp, nearA, farA, dbp, out);
}